// Round 5
// baseline (3736.489 us; speedup 1.0000x reference)
//
#include <hip/hip_runtime.h>
#include <hip/hip_bf16.h>

typedef float f32x4 __attribute__((ext_vector_type(4)));
typedef short s16x8 __attribute__((ext_vector_type(8)));
typedef int   i32x4 __attribute__((ext_vector_type(4)));
typedef _Float16 h16x8 __attribute__((ext_vector_type(8)));

#define NV 1024
#define ND 1024
#define NJ 1024
#define NB 64
#define NU 512
#define NT 513            // U+1 steps
#define G3 3072           // 3*D
#define SLOT 65536        // NB*ND elements per h slot
#define NWG 64            // recurrence workgroups
#define CANARY 0x7FFF7FFFu   // fp16 all-ones NaN pair: unreachable by f2h(h)

static __device__ __forceinline__ unsigned short f2h(float f) {
  union { _Float16 h; unsigned short u; } x; x.h = (_Float16)f;   // RNE
  return x.u;
}

// Swizzled fp16 layout (K=1024 -> 32 k-chunks of 32):
// element (r,k) -> flat ((r>>4)*32 + (k>>5))*512 + ((r&15) | (((k>>3)&3)<<4))*8 + (k&7)
// = exact mfma_f32_16x16x32_f16 A/B fragment order (64 lanes x 16B contiguous).
static __device__ __forceinline__ void unswizzle(long e, int& r, int& k) {
  long blk = e >> 9; int l = (int)((e >> 3) & 63); int j = (int)(e & 7);
  r = (int)(blk >> 5) * 16 + (l & 15);
  k = ((int)(blk & 31)) * 32 + ((l >> 4) << 3) + j;
}

__global__ void predictor_prep(const float* __restrict__ whh, const float* __restrict__ wih,
                               const float* __restrict__ em, const float* __restrict__ lw,
                               const float* __restrict__ bih, const float* __restrict__ bhh,
                               const float* __restrict__ init,
                               unsigned short* __restrict__ wh_sw, unsigned short* __restrict__ wi_sw,
                               unsigned short* __restrict__ em_sw, unsigned short* __restrict__ lw_sw,
                               float* __restrict__ bias_sum, unsigned short* __restrict__ hs,
                               unsigned int* __restrict__ flags) {
  long e = (long)blockIdx.x * 256 + threadIdx.x;
  const long nbig = 3145728, nsm = 1048576;
  if (e < nbig) { int r, k; unswizzle(e, r, k); wh_sw[e] = f2h(whh[(long)r * 1024 + k]); return; }
  e -= nbig;
  if (e < nbig) { int r, k; unswizzle(e, r, k); wi_sw[e] = f2h(wih[(long)r * 1024 + k]); return; }
  e -= nbig;
  if (e < nsm) { int r, k; unswizzle(e, r, k); em_sw[e] = f2h(em[(long)r * 1024 + k]); return; }
  e -= nsm;
  if (e < nsm) { int r, k; unswizzle(e, r, k); lw_sw[e] = f2h(lw[(long)r * 1024 + k]); return; }
  e -= nsm;
  if (e < 65536) { int r, k; unswizzle(e, r, k); hs[e] = f2h(init[k]); return; }
  e -= 65536;
  if (e < 3072) { bias_sum[e] = bih[e] + bhh[e]; return; }
  e -= 3072;
  if (e < 128) { flags[e] = 0u; return; }   // 4 packed flag lines (512 B)
  e -= 128;
  if (e < 4202496) {  // canary-fill slots 1..513 (513*65536 ushort / 8 per thread)
    s16x8 c = { (short)0x7FFF, (short)0x7FFF, (short)0x7FFF, (short)0x7FFF,
                (short)0x7FFF, (short)0x7FFF, (short)0x7FFF, (short)0x7FFF };
    *(s16x8*)(hs + 65536 + e * 8) = c;
  }
}

// Generic fp16 GEMM: out[row, nt*64 .. +64) = A_chunk @ B^T + bias (fragment layouts).
__global__ __launch_bounds__(256) void predictor_gemm(
    const unsigned short* __restrict__ A, long a_chunk_stride,
    const unsigned short* __restrict__ Bw,
    const float* __restrict__ bias, float* __restrict__ out,
    int rowmul_i, int rowmul_c, int out_stride) {
  const int nt = blockIdx.x, chunk = blockIdx.y;
  const int tid = threadIdx.x, lane = tid & 63, wave = tid >> 6;
  const unsigned short* Ab = A + (long)chunk * a_chunk_stride + wave * 16384 + lane * 8;
  const unsigned short* Bb = Bw + (long)nt * 65536 + lane * 8;
  f32x4 a0 = {0,0,0,0}, a1 = {0,0,0,0}, a2 = {0,0,0,0}, a3 = {0,0,0,0};
#pragma unroll 4
  for (int kc = 0; kc < 32; ++kc) {
    h16x8 av = __builtin_bit_cast(h16x8, *(const s16x8*)(Ab + kc * 512));
    h16x8 w0 = __builtin_bit_cast(h16x8, *(const s16x8*)(Bb + kc * 512));
    h16x8 w1 = __builtin_bit_cast(h16x8, *(const s16x8*)(Bb + 16384 + kc * 512));
    h16x8 w2 = __builtin_bit_cast(h16x8, *(const s16x8*)(Bb + 32768 + kc * 512));
    h16x8 w3 = __builtin_bit_cast(h16x8, *(const s16x8*)(Bb + 49152 + kc * 512));
    a0 = __builtin_amdgcn_mfma_f32_16x16x32_f16(av, w0, a0, 0, 0, 0);
    a1 = __builtin_amdgcn_mfma_f32_16x16x32_f16(av, w1, a1, 0, 0, 0);
    a2 = __builtin_amdgcn_mfma_f32_16x16x32_f16(av, w2, a2, 0, 0, 0);
    a3 = __builtin_amdgcn_mfma_f32_16x16x32_f16(av, w3, a3, 0, 0, 0);
  }
  const int q = lane >> 4, nl = lane & 15, colbase = nt << 6;
#pragma unroll
  for (int j = 0; j < 4; ++j) {
    int il = (wave << 4) + (q << 2) + j;
    long row = (long)il * rowmul_i + (long)chunk * rowmul_c;
    float* orow = out + row * out_stride + colbase;
    orow[nl]      = a0[j] + bias[colbase + nl];
    orow[16 + nl] = a1[j] + bias[colbase + 16 + nl];
    orow[32 + nl] = a2[j] + bias[colbase + 32 + nl];
    orow[48 + nl] = a3[j] + bias[colbase + 48 + nl];
  }
}

#define PINSTAGE(CNT, B)                                                        \
  asm volatile("s_waitcnt vmcnt(" #CNT ")"                                      \
    : "+v"(hf[(B)*8+0]), "+v"(hf[(B)*8+1]), "+v"(hf[(B)*8+2]), "+v"(hf[(B)*8+3]), \
      "+v"(hf[(B)*8+4]), "+v"(hf[(B)*8+5]), "+v"(hf[(B)*8+6]), "+v"(hf[(B)*8+7]) :: "memory")

// Canary-validate group B (safety net for the drain-free publish). The flag
// poll precedes the loads, so the first check passes unless the producer's
// flag beat its data through the fabric; then retry-reload until valid.
#define PVALID(B, CNT)                                                          \
  {                                                                             \
    PINSTAGE(CNT, B);                                                           \
    for (;;) {                                                                  \
      int ok = 1;                                                               \
      _Pragma("unroll")                                                         \
      for (int i = 0; i < 8; ++i) {                                             \
        i32x4 v = hf[(B)*8 + i];                                                \
        ok &= (v[0] != (int)CANARY) & (v[1] != (int)CANARY) &                   \
              (v[2] != (int)CANARY) & (v[3] != (int)CANARY);                    \
      }                                                                         \
      if (__all(ok)) break;                                                     \
      __builtin_amdgcn_s_sleep(1);                                              \
      _Pragma("unroll")                                                         \
      for (int i = 0; i < 8; ++i) {                                             \
        const unsigned short* a2_ = hprev + (B)*16384 + ((w<<3)+i)*512 + lane*8;\
        asm volatile("global_load_dwordx4 %0, %1, off sc1"                      \
                     : "=v"(hf[(B)*8+i]) : "v"(a2_) : "memory");                \
      }                                                                         \
      PINSTAGE(0, B);                                                           \
    }                                                                           \
  }

// Persistent recurrence v7 (= R4 structure + DRAIN-FREE PUBLISH):
//  - producer: LDS transpose (wave-private, lgkmcnt) -> 512-B coalesced sc1
//    store -> flag store IMMEDIATELY (no vmcnt between; data-first issue
//    order). The outstanding stores are retired for free by our own next
//    iteration's poll vmcnt(0).
//  - correctness net: slots are write-once and canary-filled; consumer
//    canary-validates each staged group (flag-gated, so retries are rare).
//  - flags stay packed (R4): consumer wave w polls ONE 128-B line.
__global__ __launch_bounds__(256, 1) void predictor_rnn(
    const unsigned short* __restrict__ wh_sw, const float* __restrict__ gtab,
    const int* __restrict__ y, const float* __restrict__ init,
    unsigned short* __restrict__ hs, unsigned short* __restrict__ flags) {
  __shared__ float buf[4][3][4][64][4];   // K-reduction exchange, 48 KB
  __shared__ unsigned short tbuf[1024];   // h store transpose, 2 KB (wave-private quarters)
  const int wg = blockIdx.x, tid = threadIdx.x, lane = tid & 63, w = tid >> 6;
  const int q = lane >> 4, dloc = lane & 15, dg = (wg << 4) + dloc;

  // Weight fragments -> registers (loop-invariant cached reads).
  h16x8 wrf[8], wzf[8], wnf[8];
#pragma unroll
  for (int i = 0; i < 8; ++i) {
    int kc = (w << 3) + i;
    wrf[i] = __builtin_bit_cast(h16x8, *(const s16x8*)(wh_sw + ((long)(      wg) << 14) + kc * 512 + lane * 8));
    wzf[i] = __builtin_bit_cast(h16x8, *(const s16x8*)(wh_sw + ((long)( 64 + wg) << 14) + kc * 512 + lane * 8));
    wnf[i] = __builtin_bit_cast(h16x8, *(const s16x8*)(wh_sw + ((long)(128 + wg) << 14) + kc * 512 + lane * 8));
  }
  float hreg[4];
#pragma unroll
  for (int j = 0; j < 4; ++j) hreg[j] = init[dg];

  // This wave's poll address (one ushort within its group's 128-B line) and
  // this wave's publish flag address.
  const unsigned short* fpoll = flags + (w << 6) + lane;
  unsigned short* fpub = flags + ((wg >> 4) << 6) + ((wg & 15) << 2) + w;

  for (int t = 1; t <= NT; ++t) {
    // ---- issue gate-table prefetch (drained for free by the poll) ----
    float gr[4], gz[4], gn[4];
#pragma unroll
    for (int j = 0; j < 4; ++j) {
      int b = (w << 4) + (q << 2) + j;
      int tok = (t == 1) ? 0 : y[b * NU + (t - 2)];
      const float* g = gtab + (long)tok * G3 + dg;
      asm volatile("global_load_dword %0, %1, off" : "=v"(gr[j]) : "v"(g) : "memory");
      asm volatile("global_load_dword %0, %1, off" : "=v"(gz[j]) : "v"(g + 1024) : "memory");
      asm volatile("global_load_dword %0, %1, off" : "=v"(gn[j]) : "v"(g + 2048) : "memory");
    }

    // ---- per-wave poll: ONE coalesced ushort load (single 128-B line) ----
    if (t > 1) {
      const unsigned int tm1 = (unsigned)(t - 1);
      for (;;) {
        unsigned int v;
        asm volatile("global_load_ushort %0, %1, off sc1" : "=v"(v) : "v"(fpoll) : "memory");
        asm volatile("s_waitcnt vmcnt(0)" : "+v"(v) :: "memory");
        if (__all((int)(v >= tm1))) break;
        __builtin_amdgcn_s_sleep(1);
      }
    }
    // tie gtab registers (vmcnt already 0 after the poll)
    asm volatile("s_waitcnt vmcnt(0)"
      : "+v"(gr[0]), "+v"(gr[1]), "+v"(gr[2]), "+v"(gr[3]),
        "+v"(gz[0]), "+v"(gz[1]), "+v"(gz[2]), "+v"(gz[3]),
        "+v"(gn[0]), "+v"(gn[1]), "+v"(gn[2]), "+v"(gn[3]) :: "memory");

    const unsigned short* hprev = hs + (long)(t - 1) * SLOT;
    unsigned short* hcur = hs + (long)t * SLOT;

    // ---- issue all 32 coherent h-fragment loads, consume in 4 staged groups ----
    i32x4 hf[32];
#pragma unroll
    for (int bg = 0; bg < 4; ++bg)
#pragma unroll
      for (int i = 0; i < 8; ++i) {
        const unsigned short* a = hprev + bg * 16384 + ((w << 3) + i) * 512 + lane * 8;
        asm volatile("global_load_dwordx4 %0, %1, off sc1" : "=v"(hf[bg * 8 + i]) : "v"(a) : "memory");
      }
    f32x4 aR[4], aZ[4], aN[4];
#pragma unroll
    for (int bg = 0; bg < 4; ++bg) { aR[bg] = (f32x4){0,0,0,0}; aZ[bg] = (f32x4){0,0,0,0}; aN[bg] = (f32x4){0,0,0,0}; }

    PVALID(0, 24);
#pragma unroll
    for (int i = 0; i < 8; ++i) { h16x8 a = __builtin_bit_cast(h16x8, hf[0 * 8 + i]);
      aR[0] = __builtin_amdgcn_mfma_f32_16x16x32_f16(a, wrf[i], aR[0], 0, 0, 0);
      aZ[0] = __builtin_amdgcn_mfma_f32_16x16x32_f16(a, wzf[i], aZ[0], 0, 0, 0);
      aN[0] = __builtin_amdgcn_mfma_f32_16x16x32_f16(a, wnf[i], aN[0], 0, 0, 0); }
    PVALID(1, 16);
#pragma unroll
    for (int i = 0; i < 8; ++i) { h16x8 a = __builtin_bit_cast(h16x8, hf[1 * 8 + i]);
      aR[1] = __builtin_amdgcn_mfma_f32_16x16x32_f16(a, wrf[i], aR[1], 0, 0, 0);
      aZ[1] = __builtin_amdgcn_mfma_f32_16x16x32_f16(a, wzf[i], aZ[1], 0, 0, 0);
      aN[1] = __builtin_amdgcn_mfma_f32_16x16x32_f16(a, wnf[i], aN[1], 0, 0, 0); }
    PVALID(2, 8);
#pragma unroll
    for (int i = 0; i < 8; ++i) { h16x8 a = __builtin_bit_cast(h16x8, hf[2 * 8 + i]);
      aR[2] = __builtin_amdgcn_mfma_f32_16x16x32_f16(a, wrf[i], aR[2], 0, 0, 0);
      aZ[2] = __builtin_amdgcn_mfma_f32_16x16x32_f16(a, wzf[i], aZ[2], 0, 0, 0);
      aN[2] = __builtin_amdgcn_mfma_f32_16x16x32_f16(a, wnf[i], aN[2], 0, 0, 0); }
    PVALID(3, 0);
#pragma unroll
    for (int i = 0; i < 8; ++i) { h16x8 a = __builtin_bit_cast(h16x8, hf[3 * 8 + i]);
      aR[3] = __builtin_amdgcn_mfma_f32_16x16x32_f16(a, wrf[i], aR[3], 0, 0, 0);
      aZ[3] = __builtin_amdgcn_mfma_f32_16x16x32_f16(a, wzf[i], aZ[3], 0, 0, 0);
      aN[3] = __builtin_amdgcn_mfma_f32_16x16x32_f16(a, wnf[i], aN[3], 0, 0, 0); }

    // ---- cross-wave K-reduction via LDS ----
#pragma unroll
    for (int b2 = 0; b2 < 4; ++b2)
      if (b2 != w) {
        *(f32x4*)&buf[w][0][b2][lane][0] = aR[b2];
        *(f32x4*)&buf[w][1][b2][lane][0] = aZ[b2];
        *(f32x4*)&buf[w][2][b2][lane][0] = aN[b2];
      }
    __syncthreads();
    f32x4 sR = aR[w], sZ = aZ[w], sN = aN[w];
#pragma unroll
    for (int v = 0; v < 4; ++v)
      if (v != w) {
        sR += *(const f32x4*)&buf[v][0][w][lane][0];
        sZ += *(const f32x4*)&buf[v][1][w][lane][0];
        sN += *(const f32x4*)&buf[v][2][w][lane][0];
      }
    __syncthreads();   // buf WAR protection vs next iteration's writes

    // ---- gate epilogue; fp32 h chain in registers; fp16 h to wave-private tbuf ----
#pragma unroll
    for (int j = 0; j < 4; ++j) {
      float r = 1.f / (1.f + __expf(-(gr[j] + sR[j])));
      float z = 1.f / (1.f + __expf(-(gz[j] + sZ[j])));
      float np = gn[j] + r * sN[j];
      float e2 = __expf(-2.f * fabsf(np));              // overflow-safe tanh
      float tn = (1.f - e2) / (1.f + e2);
      tn = np < 0.f ? -tn : tn;
      float hnew = (1.f - z) * tn + z * hreg[j];
      hreg[j] = hnew;
      tbuf[(w << 8) + ((((q << 2) + j) | ((dloc >> 3) << 4)) << 3) + (dloc & 7)] = f2h(hnew);
    }
    // wave-private transpose: wave-local LDS ordering is enough (no barrier)
    asm volatile("s_waitcnt lgkmcnt(0)" ::: "memory");

    // ---- drain-free publish: 512-B store then 2-B flag, no vmcnt between ----
    {
      unsigned long long pv = *(const unsigned long long*)(tbuf + (w << 8) + lane * 4);
      unsigned short* gp = hcur + ((long)(w * 32 + (wg >> 1)) << 9) + ((wg & 1) << 8) + lane * 4;
      asm volatile("global_store_dwordx2 %0, %1, off sc1" :: "v"(gp), "v"(pv) : "memory");
      if (lane == 0)
        asm volatile("global_store_short %0, %1, off sc1" :: "v"(fpub), "v"((unsigned)t) : "memory");
      // no drain: consumers canary-validate; our next poll's vmcnt(0) retires these.
    }
  }
}

extern "C" void kernel_launch(void* const* d_in, const int* in_sizes, int n_in,
                              void* d_out, int out_size, void* d_ws, size_t ws_size,
                              hipStream_t stream) {
  const int*   y    = (const int*)d_in[0];
  const float* em   = (const float*)d_in[1];
  const float* wih  = (const float*)d_in[2];
  const float* bih  = (const float*)d_in[3];
  const float* whh  = (const float*)d_in[4];
  const float* bhh  = (const float*)d_in[5];
  const float* lw   = (const float*)d_in[6];
  const float* lb   = (const float*)d_in[7];
  const float* init = (const float*)d_in[8];
  float* out = (float*)d_out;

  char* ws = (char*)d_ws;
  size_t off = 0;
  auto alloc = [&](size_t n) { void* p = ws + off; off += (n + 255) & ~(size_t)255; return p; };
  unsigned short* wh_sw   = (unsigned short*)alloc(6291456);    // W_hh fp16 swizzled
  unsigned short* wi_sw   = (unsigned short*)alloc(6291456);    // W_ih fp16 swizzled
  unsigned short* em_sw   = (unsigned short*)alloc(2097152);    // embed fp16 swizzled
  unsigned short* lw_sw   = (unsigned short*)alloc(2097152);    // linear_w fp16 swizzled
  float*          gtab    = (float*)alloc(12582912);            // [V,3072] token gate table
  float*          bias_sum= (float*)alloc(12288);               // bias_ih + bias_hh
  unsigned int*   flags   = (unsigned int*)alloc(512);          // 4 packed ushort flag lines
  unsigned short* hs      = (unsigned short*)alloc(67371008UL); // 514 h slots, fp16 swizzled
  (void)ws_size; (void)in_sizes; (void)n_in; (void)out_size;

  predictor_prep<<<dim3(49453), dim3(256), 0, stream>>>(
      whh, wih, em, lw, bih, bhh, init, wh_sw, wi_sw, em_sw, lw_sw, bias_sum, hs, flags);
  predictor_gemm<<<dim3(48, 16), dim3(256), 0, stream>>>(
      em_sw, 65536L, wi_sw, bias_sum, gtab, /*rowmul_i=*/1, /*rowmul_c=*/64, /*stride=*/3072);
  predictor_rnn<<<dim3(NWG), dim3(256), 0, stream>>>(
      wh_sw, gtab, y, init, hs, (unsigned short*)flags);
  predictor_gemm<<<dim3(16, 513), dim3(256), 0, stream>>>(
      hs + 65536, 65536L, lw_sw, lb, out, /*rowmul_i=*/513, /*rowmul_c=*/1, /*stride=*/1024);
}

// Round 6
// 2876.090 us; speedup vs baseline: 1.2992x; 1.2992x over previous
//
#include <hip/hip_runtime.h>
#include <hip/hip_bf16.h>

typedef float f32x4 __attribute__((ext_vector_type(4)));
typedef short s16x8 __attribute__((ext_vector_type(8)));
typedef int   i32x4 __attribute__((ext_vector_type(4)));
typedef _Float16 h16x8 __attribute__((ext_vector_type(8)));

#define NV 1024
#define ND 1024
#define NJ 1024
#define NB 64
#define NU 512
#define NT 513            // U+1 steps
#define G3 3072           // 3*D
#define SLOT 65536        // NB*ND elements per h slot
#define NWG 64            // recurrence workgroups

static __device__ __forceinline__ unsigned short f2h(float f) {
  union { _Float16 h; unsigned short u; } x; x.h = (_Float16)f;   // RNE
  return x.u;
}

// Swizzled fp16 layout (K=1024 -> 32 k-chunks of 32):
// element (r,k) -> flat ((r>>4)*32 + (k>>5))*512 + ((r&15) | (((k>>3)&3)<<4))*8 + (k&7)
// = exact mfma_f32_16x16x32_f16 A/B fragment order (64 lanes x 16B contiguous).
static __device__ __forceinline__ void unswizzle(long e, int& r, int& k) {
  long blk = e >> 9; int l = (int)((e >> 3) & 63); int j = (int)(e & 7);
  r = (int)(blk >> 5) * 16 + (l & 15);
  k = ((int)(blk & 31)) * 32 + ((l >> 4) << 3) + j;
}

__global__ void predictor_prep(const float* __restrict__ whh, const float* __restrict__ wih,
                               const float* __restrict__ em, const float* __restrict__ lw,
                               const float* __restrict__ bih, const float* __restrict__ bhh,
                               const float* __restrict__ init,
                               unsigned short* __restrict__ wh_sw, unsigned short* __restrict__ wi_sw,
                               unsigned short* __restrict__ em_sw, unsigned short* __restrict__ lw_sw,
                               float* __restrict__ bias_sum, unsigned short* __restrict__ hs,
                               unsigned int* __restrict__ flags) {
  long e = (long)blockIdx.x * 256 + threadIdx.x;
  const long nbig = 3145728, nsm = 1048576;
  if (e < nbig) { int r, k; unswizzle(e, r, k); wh_sw[e] = f2h(whh[(long)r * 1024 + k]); return; }
  e -= nbig;
  if (e < nbig) { int r, k; unswizzle(e, r, k); wi_sw[e] = f2h(wih[(long)r * 1024 + k]); return; }
  e -= nbig;
  if (e < nsm) { int r, k; unswizzle(e, r, k); em_sw[e] = f2h(em[(long)r * 1024 + k]); return; }
  e -= nsm;
  if (e < nsm) { int r, k; unswizzle(e, r, k); lw_sw[e] = f2h(lw[(long)r * 1024 + k]); return; }
  e -= nsm;
  if (e < 65536) { int r, k; unswizzle(e, r, k); hs[e] = f2h(init[k]); return; }
  e -= 65536;
  if (e < 3072) { bias_sum[e] = bih[e] + bhh[e]; return; }
  e -= 3072;
  if (e < 128) flags[e] = 0u;   // 4 packed flag lines (512 B)
}

// Generic fp16 GEMM: out[row, nt*64 .. +64) = A_chunk @ B^T + bias (fragment layouts).
__global__ __launch_bounds__(256) void predictor_gemm(
    const unsigned short* __restrict__ A, long a_chunk_stride,
    const unsigned short* __restrict__ Bw,
    const float* __restrict__ bias, float* __restrict__ out,
    int rowmul_i, int rowmul_c, int out_stride) {
  const int nt = blockIdx.x, chunk = blockIdx.y;
  const int tid = threadIdx.x, lane = tid & 63, wave = tid >> 6;
  const unsigned short* Ab = A + (long)chunk * a_chunk_stride + wave * 16384 + lane * 8;
  const unsigned short* Bb = Bw + (long)nt * 65536 + lane * 8;
  f32x4 a0 = {0,0,0,0}, a1 = {0,0,0,0}, a2 = {0,0,0,0}, a3 = {0,0,0,0};
#pragma unroll 4
  for (int kc = 0; kc < 32; ++kc) {
    h16x8 av = __builtin_bit_cast(h16x8, *(const s16x8*)(Ab + kc * 512));
    h16x8 w0 = __builtin_bit_cast(h16x8, *(const s16x8*)(Bb + kc * 512));
    h16x8 w1 = __builtin_bit_cast(h16x8, *(const s16x8*)(Bb + 16384 + kc * 512));
    h16x8 w2 = __builtin_bit_cast(h16x8, *(const s16x8*)(Bb + 32768 + kc * 512));
    h16x8 w3 = __builtin_bit_cast(h16x8, *(const s16x8*)(Bb + 49152 + kc * 512));
    a0 = __builtin_amdgcn_mfma_f32_16x16x32_f16(av, w0, a0, 0, 0, 0);
    a1 = __builtin_amdgcn_mfma_f32_16x16x32_f16(av, w1, a1, 0, 0, 0);
    a2 = __builtin_amdgcn_mfma_f32_16x16x32_f16(av, w2, a2, 0, 0, 0);
    a3 = __builtin_amdgcn_mfma_f32_16x16x32_f16(av, w3, a3, 0, 0, 0);
  }
  const int q = lane >> 4, nl = lane & 15, colbase = nt << 6;
#pragma unroll
  for (int j = 0; j < 4; ++j) {
    int il = (wave << 4) + (q << 2) + j;
    long row = (long)il * rowmul_i + (long)chunk * rowmul_c;
    float* orow = out + row * out_stride + colbase;
    orow[nl]      = a0[j] + bias[colbase + nl];
    orow[16 + nl] = a1[j] + bias[colbase + 16 + nl];
    orow[32 + nl] = a2[j] + bias[colbase + 32 + nl];
    orow[48 + nl] = a3[j] + bias[colbase + 48 + nl];
  }
}

#define PINSTAGE(CNT, B)                                                        \
  asm volatile("s_waitcnt vmcnt(" #CNT ")"                                      \
    : "+v"(hf[(B)*8+0]), "+v"(hf[(B)*8+1]), "+v"(hf[(B)*8+2]), "+v"(hf[(B)*8+3]), \
      "+v"(hf[(B)*8+4]), "+v"(hf[(B)*8+5]), "+v"(hf[(B)*8+6]), "+v"(hf[(B)*8+7]) :: "memory")

// Persistent recurrence v8: BATCH-GROUP-PER-WAVE, WEIGHTS IN LDS, NO BARRIERS.
//  - WG wg owns out-dims [wg*16,+16); its full weight slice (3 gates x 16 dims
//    x K=1024 = 96 KB fp16) is staged once into LDS, fragment-ordered.
//  - wave w owns batch group [16w,+16) COMPLETELY: all 32 k-chunks, full gate
//    sums in 3 f32x4 accumulators -> no cross-wave K-reduction, no syncthreads
//    in the steady loop. The computation splits into 4 fully independent
//    recurrence chains (one per batch group of 16), each a 64-wave ring.
//  - flags: line w (128 B) = layer-w producers; (wg,w) publishes ushort at
//    offset wg; consumer wave w polls line w with one coalesced load.
//  - publish path unchanged from R4 (proven): wave-private LDS transpose ->
//    512-B coalesced sc1 store -> vmcnt(0) drain -> 2-B flag.
//  - h loads: one contiguous 16-KB block per wave, staged vmcnt(24/16/8/0)
//    against 12 gtab loads issued ahead (same constants as R4).
__global__ __launch_bounds__(256, 1) void predictor_rnn(
    const unsigned short* __restrict__ wh_sw, const float* __restrict__ gtab,
    const int* __restrict__ y, const float* __restrict__ init,
    unsigned short* __restrict__ hs, unsigned short* __restrict__ flags) {
  __shared__ unsigned short wlds[49152];  // 3 gates x 32 kc x 512 elems, 96 KB
  __shared__ unsigned short tbuf[1024];   // h store transpose, 2 KB (wave-private quarters)
  const int wg = blockIdx.x, tid = threadIdx.x, lane = tid & 63, w = tid >> 6;
  const int q = lane >> 4, dloc = lane & 15, dg = (wg << 4) + dloc;

  // ---- stage this WG's weight slice into LDS (3 contiguous 32-KB blocks) ----
  for (int g = 0; g < 3; ++g) {
    const unsigned short* src = wh_sw + ((long)(g * 64 + wg) << 14);
#pragma unroll
    for (int i = 0; i < 8; ++i) {
      int c = i * 256 + tid;                  // 2048 chunks of 8 elems per gate
      *(s16x8*)&wlds[g * 16384 + c * 8] = *(const s16x8*)&src[c * 8];
    }
  }
  __syncthreads();   // weights visible to all waves; only barrier in the kernel

  float hreg[4];
#pragma unroll
  for (int j = 0; j < 4; ++j) hreg[j] = init[dg];

  // Layer-w flag line: producer (wg,w) -> ushort offset wg; consumer polls lane=wg'.
  const unsigned short* fpoll = flags + (w << 6) + lane;
  unsigned short* fpub = flags + (w << 6) + wg;
  const s16x8* wbase = (const s16x8*)wlds + lane;   // + kc*64 (+2048/gate) below

  for (int t = 1; t <= NT; ++t) {
    // ---- issue gate-table prefetch (12 loads; drained for free by the poll) ----
    float gr[4], gz[4], gn[4];
#pragma unroll
    for (int j = 0; j < 4; ++j) {
      int b = (w << 4) + (q << 2) + j;
      int tok = (t == 1) ? 0 : y[b * NU + (t - 2)];
      const float* g = gtab + (long)tok * G3 + dg;
      asm volatile("global_load_dword %0, %1, off" : "=v"(gr[j]) : "v"(g) : "memory");
      asm volatile("global_load_dword %0, %1, off" : "=v"(gz[j]) : "v"(g + 1024) : "memory");
      asm volatile("global_load_dword %0, %1, off" : "=v"(gn[j]) : "v"(g + 2048) : "memory");
    }

    // ---- per-wave poll: ONE coalesced ushort load (layer-w line) ----
    if (t > 1) {
      const unsigned int tm1 = (unsigned)(t - 1);
      for (;;) {
        unsigned int v;
        asm volatile("global_load_ushort %0, %1, off sc1" : "=v"(v) : "v"(fpoll) : "memory");
        asm volatile("s_waitcnt vmcnt(0)" : "+v"(v) :: "memory");
        if (__all((int)(v >= tm1))) break;
        __builtin_amdgcn_s_sleep(1);
      }
    }
    // tie gtab registers (vmcnt already 0 after the poll)
    asm volatile("s_waitcnt vmcnt(0)"
      : "+v"(gr[0]), "+v"(gr[1]), "+v"(gr[2]), "+v"(gr[3]),
        "+v"(gz[0]), "+v"(gz[1]), "+v"(gz[2]), "+v"(gz[3]),
        "+v"(gn[0]), "+v"(gn[1]), "+v"(gn[2]), "+v"(gn[3]) :: "memory");

    // own batch group's full h row-block: contiguous 16 KB
    const unsigned short* hprev = hs + (long)(t - 1) * SLOT + (w << 14);
    unsigned short* hcur = hs + (long)t * SLOT;

    // ---- issue all 32 h-fragment loads, consume in 4 staged groups ----
    i32x4 hf[32];
#pragma unroll
    for (int i = 0; i < 32; ++i) {
      const unsigned short* a = hprev + i * 512 + lane * 8;
      asm volatile("global_load_dwordx4 %0, %1, off sc1" : "=v"(hf[i]) : "v"(a) : "memory");
    }
    f32x4 aR = {0,0,0,0}, aZ = {0,0,0,0}, aN = {0,0,0,0};
    {
      PINSTAGE(24, 0);
#pragma unroll
      for (int i = 0; i < 8; ++i) { int kc = i; h16x8 a = __builtin_bit_cast(h16x8, hf[kc]);
        h16x8 wr = __builtin_bit_cast(h16x8, wbase[kc * 64]);
        h16x8 wz = __builtin_bit_cast(h16x8, wbase[2048 + kc * 64]);
        h16x8 wn = __builtin_bit_cast(h16x8, wbase[4096 + kc * 64]);
        aR = __builtin_amdgcn_mfma_f32_16x16x32_f16(a, wr, aR, 0, 0, 0);
        aZ = __builtin_amdgcn_mfma_f32_16x16x32_f16(a, wz, aZ, 0, 0, 0);
        aN = __builtin_amdgcn_mfma_f32_16x16x32_f16(a, wn, aN, 0, 0, 0); }
      PINSTAGE(16, 1);
#pragma unroll
      for (int i = 0; i < 8; ++i) { int kc = 8 + i; h16x8 a = __builtin_bit_cast(h16x8, hf[kc]);
        h16x8 wr = __builtin_bit_cast(h16x8, wbase[kc * 64]);
        h16x8 wz = __builtin_bit_cast(h16x8, wbase[2048 + kc * 64]);
        h16x8 wn = __builtin_bit_cast(h16x8, wbase[4096 + kc * 64]);
        aR = __builtin_amdgcn_mfma_f32_16x16x32_f16(a, wr, aR, 0, 0, 0);
        aZ = __builtin_amdgcn_mfma_f32_16x16x32_f16(a, wz, aZ, 0, 0, 0);
        aN = __builtin_amdgcn_mfma_f32_16x16x32_f16(a, wn, aN, 0, 0, 0); }
      PINSTAGE(8, 2);
#pragma unroll
      for (int i = 0; i < 8; ++i) { int kc = 16 + i; h16x8 a = __builtin_bit_cast(h16x8, hf[kc]);
        h16x8 wr = __builtin_bit_cast(h16x8, wbase[kc * 64]);
        h16x8 wz = __builtin_bit_cast(h16x8, wbase[2048 + kc * 64]);
        h16x8 wn = __builtin_bit_cast(h16x8, wbase[4096 + kc * 64]);
        aR = __builtin_amdgcn_mfma_f32_16x16x32_f16(a, wr, aR, 0, 0, 0);
        aZ = __builtin_amdgcn_mfma_f32_16x16x32_f16(a, wz, aZ, 0, 0, 0);
        aN = __builtin_amdgcn_mfma_f32_16x16x32_f16(a, wn, aN, 0, 0, 0); }
      PINSTAGE(0, 3);
#pragma unroll
      for (int i = 0; i < 8; ++i) { int kc = 24 + i; h16x8 a = __builtin_bit_cast(h16x8, hf[kc]);
        h16x8 wr = __builtin_bit_cast(h16x8, wbase[kc * 64]);
        h16x8 wz = __builtin_bit_cast(h16x8, wbase[2048 + kc * 64]);
        h16x8 wn = __builtin_bit_cast(h16x8, wbase[4096 + kc * 64]);
        aR = __builtin_amdgcn_mfma_f32_16x16x32_f16(a, wr, aR, 0, 0, 0);
        aZ = __builtin_amdgcn_mfma_f32_16x16x32_f16(a, wz, aZ, 0, 0, 0);
        aN = __builtin_amdgcn_mfma_f32_16x16x32_f16(a, wn, aN, 0, 0, 0); }
    }

    // ---- gate epilogue (full sums already in acc); fp16 h to wave-private tbuf ----
#pragma unroll
    for (int j = 0; j < 4; ++j) {
      float r = 1.f / (1.f + __expf(-(gr[j] + aR[j])));
      float z = 1.f / (1.f + __expf(-(gz[j] + aZ[j])));
      float np = gn[j] + r * aN[j];
      float e2 = __expf(-2.f * fabsf(np));              // overflow-safe tanh
      float tn = (1.f - e2) / (1.f + e2);
      tn = np < 0.f ? -tn : tn;
      float hnew = (1.f - z) * tn + z * hreg[j];
      hreg[j] = hnew;
      tbuf[(w << 8) + ((((q << 2) + j) | ((dloc >> 3) << 4)) << 3) + (dloc & 7)] = f2h(hnew);
    }
    // wave-private transpose: wave-local LDS ordering is enough (no barrier)
    asm volatile("s_waitcnt lgkmcnt(0)" ::: "memory");

    // ---- per-wave publish: 512-B coalesced store -> drain -> 2-B flag ----
    {
      unsigned long long pv = *(const unsigned long long*)(tbuf + (w << 8) + lane * 4);
      unsigned short* gp = hcur + ((long)(w * 32 + (wg >> 1)) << 9) + ((wg & 1) << 8) + lane * 4;
      asm volatile("global_store_dwordx2 %0, %1, off sc1" :: "v"(gp), "v"(pv) : "memory");
      asm volatile("s_waitcnt vmcnt(0)" ::: "memory");
      if (lane == 0)
        asm volatile("global_store_short %0, %1, off sc1" :: "v"(fpub), "v"((unsigned)t) : "memory");
    }
  }
}

extern "C" void kernel_launch(void* const* d_in, const int* in_sizes, int n_in,
                              void* d_out, int out_size, void* d_ws, size_t ws_size,
                              hipStream_t stream) {
  const int*   y    = (const int*)d_in[0];
  const float* em   = (const float*)d_in[1];
  const float* wih  = (const float*)d_in[2];
  const float* bih  = (const float*)d_in[3];
  const float* whh  = (const float*)d_in[4];
  const float* bhh  = (const float*)d_in[5];
  const float* lw   = (const float*)d_in[6];
  const float* lb   = (const float*)d_in[7];
  const float* init = (const float*)d_in[8];
  float* out = (float*)d_out;

  char* ws = (char*)d_ws;
  size_t off = 0;
  auto alloc = [&](size_t n) { void* p = ws + off; off += (n + 255) & ~(size_t)255; return p; };
  unsigned short* wh_sw   = (unsigned short*)alloc(6291456);    // W_hh fp16 swizzled
  unsigned short* wi_sw   = (unsigned short*)alloc(6291456);    // W_ih fp16 swizzled
  unsigned short* em_sw   = (unsigned short*)alloc(2097152);    // embed fp16 swizzled
  unsigned short* lw_sw   = (unsigned short*)alloc(2097152);    // linear_w fp16 swizzled
  float*          gtab    = (float*)alloc(12582912);            // [V,3072] token gate table
  float*          bias_sum= (float*)alloc(12288);               // bias_ih + bias_hh
  unsigned int*   flags   = (unsigned int*)alloc(512);          // 4 packed ushort flag lines
  unsigned short* hs      = (unsigned short*)alloc(67371008UL); // 514 h slots, fp16 swizzled
  (void)ws_size; (void)in_sizes; (void)n_in; (void)out_size;

  predictor_prep<<<dim3(33037), dim3(256), 0, stream>>>(
      whh, wih, em, lw, bih, bhh, init, wh_sw, wi_sw, em_sw, lw_sw, bias_sum, hs, flags);
  predictor_gemm<<<dim3(48, 16), dim3(256), 0, stream>>>(
      em_sw, 65536L, wi_sw, bias_sum, gtab, /*rowmul_i=*/1, /*rowmul_c=*/64, /*stride=*/3072);
  predictor_rnn<<<dim3(NWG), dim3(256), 0, stream>>>(
      wh_sw, gtab, y, init, hs, (unsigned short*)flags);
  predictor_gemm<<<dim3(16, 513), dim3(256), 0, stream>>>(
      hs + 65536, 65536L, lw_sw, lb, out, /*rowmul_i=*/513, /*rowmul_c=*/1, /*stride=*/1024);
}